// Round 3
// baseline (1509.523 us; speedup 1.0000x reference)
//
#include <hip/hip_runtime.h>

// HDC encoder = row gather: out[i, :] = vocab[tokens[i], :]
// N_TOKENS = 8192, DIMENSIONS = 10000, VOCAB = 32000, fp32.
// Pure memory-bound copy. One block per token row; float4 vectorized
// copy (16 B/lane). Row length 10000 floats = 2500 float4 (exact).

#define HDC_DIMS 10000
#define HDC_VEC4 (HDC_DIMS / 4)   // 2500 float4 per row

__global__ __launch_bounds__(256) void HDCEncoder_gather_kernel(
    const int* __restrict__ tokens,
    const float4* __restrict__ vocab,
    float4* __restrict__ out,
    int n_tokens)
{
    const int row = blockIdx.x;
    if (row >= n_tokens) return;
    // tokens[row] is uniform across the block -> compiler emits scalar load.
    const int tok = tokens[row];
    const float4* __restrict__ src = vocab + (size_t)tok * HDC_VEC4;
    float4* __restrict__ dst = out + (size_t)row * HDC_VEC4;
    // 2500 float4 per row, 256 threads -> ~9.77 iters/thread, coalesced.
    for (int j = threadIdx.x; j < HDC_VEC4; j += 256) {
        dst[j] = src[j];
    }
}

extern "C" void kernel_launch(void* const* d_in, const int* in_sizes, int n_in,
                              void* d_out, int out_size, void* d_ws, size_t ws_size,
                              hipStream_t stream)
{
    const int* tokens = (const int*)d_in[0];          // int32 tokens [N_TOKENS]
    const float4* vocab = (const float4*)d_in[1];     // fp32 vocab [VOCAB, DIMS]
    float4* out = (float4*)d_out;                     // fp32 out [N_TOKENS, DIMS]
    const int n_tokens = in_sizes[0];

    dim3 grid(n_tokens);
    dim3 block(256);
    HDCEncoder_gather_kernel<<<grid, block, 0, stream>>>(tokens, vocab, out, n_tokens);
}

// Round 5
// 1507.741 us; speedup vs baseline: 1.0012x; 1.0012x over previous
//
#include <hip/hip_runtime.h>

// HDC encoder = row gather: out[i, :] = vocab[tokens[i], :]
// N_TOKENS = 8192, DIMENSIONS = 10000, VOCAB = 32000, fp32.
// Memory-bound copy: ~290-330 MB gather-read + 327.7 MB write -> ~105 us
// floor at 6.3 TB/s achievable.
//
// (1) nontemporal stores for the write-once output (keeps vocab rows
// resident in L2/LLC for duplicate tokens), (2) 2 blocks per row with
// 4 loads issued back-to-back before stores (memory-level parallelism).
// Native clang vector type: __builtin_nontemporal_store rejects
// HIP_vector_type<float,4> (Round 4 compile error).

typedef float f32x4 __attribute__((ext_vector_type(4)));

#define HDC_DIMS  10000
#define HDC_VEC4  (HDC_DIMS / 4)   // 2500 f32x4 per row
#define HALF_VEC4 (HDC_VEC4 / 2)   // 1250 f32x4 per half-row
// 1250 = 4*256 + 226: 4 full strides of 256 threads + a 226-thread tail.

__global__ __launch_bounds__(256) void HDCEncoder_gather_kernel(
    const int* __restrict__ tokens,
    const f32x4* __restrict__ vocab,
    f32x4* __restrict__ out,
    int n_tokens)
{
    const int row  = blockIdx.x >> 1;
    const int half = blockIdx.x & 1;
    if (row >= n_tokens) return;
    // tokens[row] is block-uniform -> scalar load.
    const int tok = tokens[row];
    const f32x4* __restrict__ src = vocab + (size_t)tok * HDC_VEC4 + half * HALF_VEC4;
    f32x4* __restrict__ dst       = out   + (size_t)row * HDC_VEC4 + half * HALF_VEC4;

    const int t = threadIdx.x;
    // Batch 4 loads first -> 4 outstanding global_load_dwordx4 per lane.
    f32x4 v0 = src[t];
    f32x4 v1 = src[t + 256];
    f32x4 v2 = src[t + 512];
    f32x4 v3 = src[t + 768];
    __builtin_nontemporal_store(v0, &dst[t]);
    __builtin_nontemporal_store(v1, &dst[t + 256]);
    __builtin_nontemporal_store(v2, &dst[t + 512]);
    __builtin_nontemporal_store(v3, &dst[t + 768]);
    if (t < HALF_VEC4 - 1024) {   // 226-thread tail
        f32x4 v4 = src[t + 1024];
        __builtin_nontemporal_store(v4, &dst[t + 1024]);
    }
}

extern "C" void kernel_launch(void* const* d_in, const int* in_sizes, int n_in,
                              void* d_out, int out_size, void* d_ws, size_t ws_size,
                              hipStream_t stream)
{
    const int* tokens   = (const int*)d_in[0];      // int32 tokens [N_TOKENS]
    const f32x4* vocab  = (const f32x4*)d_in[1];    // fp32 vocab [VOCAB, DIMS]
    f32x4* out          = (f32x4*)d_out;            // fp32 out [N_TOKENS, DIMS]
    const int n_tokens  = in_sizes[0];

    dim3 grid(2 * n_tokens);   // 2 blocks per row
    dim3 block(256);
    HDCEncoder_gather_kernel<<<grid, block, 0, stream>>>(tokens, vocab, out, n_tokens);
}